// Round 5
// baseline (270.719 us; speedup 1.0000x reference)
//
#include <hip/hip_runtime.h>
#include <hip/hip_bf16.h>

#define NN 2048
#define KK 8
#define DD 32
#define ZSZ (KK * NN * DD)  // 524288

typedef __attribute__((ext_vector_type(8))) short short8;
typedef __attribute__((ext_vector_type(4))) float f32x4;
typedef __attribute__((ext_vector_type(4))) unsigned int u32x4;

union UU { u32x4 q; short8 v; unsigned int u[4]; };

#define SELHI 0x07060302u
#define SELLO 0x05040100u
#define PSTR 36  // padded P row stride (u32): conflict-free b128 reads / 2-way writes

__device__ __forceinline__ unsigned int prm(unsigned int a, unsigned int b, unsigned int sel) {
  return __builtin_amdgcn_perm(a, b, sel);
}
// round-to-nearest-even fp32 -> bf16 (scalar, used in rp only)
__device__ __forceinline__ unsigned int bfr(float x) {
  unsigned int u = __float_as_uint(x);
  return (u + 0x7fffu + ((u >> 16) & 1u)) >> 16;
}
// a->lo16, b->hi16 via v_cvt_pk_bf16_f32 (RNE)
__device__ __forceinline__ unsigned int packp(float a, float b) {
  union { __hip_bfloat162 h; unsigned int u; } cv;
  cv.h = __float22bfloat162_rn(make_float2(a, b));
  return cv.u;
}
__device__ __forceinline__ f32x4 MF(short8 a, short8 b, f32x4 c) {
  return __builtin_amdgcn_mfma_f32_16x16x32_bf16(a, b, c, 0, 0, 0);
}
__device__ __forceinline__ short8 as_s8(u32x4 x) { UU u; u.q = x; return u.v; }

// ------- merged: proj (blocks 0..NN) + adj bitmask pack (blocks NN..NN+256) -------
__global__ __launch_bounds__(256) void pm_kernel(const float* __restrict__ feat,
                                                 const float* __restrict__ W,
                                                 const float* __restrict__ bias,
                                                 float* __restrict__ Z,
                                                 const int* __restrict__ adj,
                                                 unsigned int* __restrict__ mbits) {
  const int t = threadIdx.x;
  if (blockIdx.x < NN) {
    __shared__ float f[128];
    const int n = blockIdx.x;
    if (t < 128) f[t] = feat[n * 128 + t];
    __syncthreads();
    const int k = t >> 5, c = t & 31;
    float s = bias[k * DD + c];
    const float* w = W + (k * 128) * DD + c;
#pragma unroll 16
    for (int d = 0; d < 128; ++d) s = fmaf(f[d], w[d * DD], s);
    float sq = s * s;
#pragma unroll
    for (int off = 16; off > 0; off >>= 1) sq += __shfl_xor(sq, off, 32);
    Z[(k * NN + n) * DD + c] = s / fmaxf(sqrtf(sq), 1e-12f);
  } else {
    const int gid = (blockIdx.x - NN) * 4 + (t >> 6);
    const int lane = t & 63;
    for (int it = 0; it < 64; ++it) {
      int idx = gid * 4096 + it * 64 + lane;
      int v = adj[idx];
      unsigned long long b = __ballot(v > 0);
      if (lane == 0) mbits[idx >> 5] = (unsigned int)b;
      if (lane == 32) mbits[idx >> 5] = (unsigned int)(b >> 32);
    }
  }
}

// ------- fused: Z = l2norm(Zin + sum partials); write Z fp32 + hi plane + hi^T -------
__global__ __launch_bounds__(256) void rp_kernel(const float* __restrict__ Zin,
                                                 const float* __restrict__ part, int nc,
                                                 float* __restrict__ Zout,
                                                 unsigned short* __restrict__ Zghi,
                                                 unsigned short* __restrict__ Zthi) {
  __shared__ unsigned short T[DD][33];
  const int t = threadIdx.x;
  const int k = blockIdx.x >> 6, mt = blockIdx.x & 63;
  const int m0 = mt * 32;
  const int mloc = t >> 3, c4 = t & 7;
  const size_t idx = (size_t)(k * NN + m0 + mloc) * DD + 4 * c4;
  float4 v = *(const float4*)&Zin[idx];
  for (int j = 0; j < nc; ++j) {
    float4 p = *(const float4*)&part[(size_t)j * ZSZ + idx];
    v.x += p.x; v.y += p.y; v.z += p.z; v.w += p.w;
  }
  float sq = v.x * v.x + v.y * v.y + v.z * v.z + v.w * v.w;
  sq += __shfl_xor(sq, 1, 8);
  sq += __shfl_xor(sq, 2, 8);
  sq += __shfl_xor(sq, 4, 8);
  const float sc = 1.0f / fmaxf(sqrtf(sq), 1e-12f);
  float z[4] = {v.x * sc, v.y * sc, v.z * sc, v.w * sc};
  if (nc) *(float4*)&Zout[idx] = make_float4(z[0], z[1], z[2], z[3]);
  unsigned int hi[4];
#pragma unroll
  for (int e = 0; e < 4; ++e) {
    hi[e] = bfr(z[e]);
    T[4 * c4 + e][mloc] = (unsigned short)hi[e];
  }
  *(uint2*)&Zghi[idx] = make_uint2(hi[0] | (hi[1] << 16), hi[2] | (hi[3] << 16));
  __syncthreads();
  const int cloc = t >> 3, m4 = t & 7;
  unsigned int o0 = (unsigned int)T[cloc][4 * m4 + 0] | ((unsigned int)T[cloc][4 * m4 + 1] << 16);
  unsigned int o1 = (unsigned int)T[cloc][4 * m4 + 2] | ((unsigned int)T[cloc][4 * m4 + 3] << 16);
  *(uint2*)&Zthi[(size_t)k * DD * NN + (size_t)cloc * NN + m0 + 4 * m4] = make_uint2(o0, o1);
}

// ---------------- fused MFMA iteration: gram + softmax(k) + aggregate ----------------
// grid (32 n-blocks, NC chunks), block 256 (4 waves x 16 n-rows).
// No staging, no barriers: all MFMA B-operands stream from L1/L2 (Z planes are 1 MB,
// L2-resident). LDS = per-wave, per-kp P buffers only (C->A layout round-trip).
__global__ __launch_bounds__(256, 2) void iter_kernel(const unsigned short* __restrict__ Zghi,
                                                      const unsigned short* __restrict__ Zthi,
                                                      const unsigned int* __restrict__ mbits,
                                                      float* __restrict__ part, int nsteps) {
  __shared__ __align__(16) unsigned int Plds[4 * 4 * 16 * PSTR];  // 36 KB
  const int t = threadIdx.x;
  const int w = t >> 6;
  const int lane = t & 63;
  const int l15 = lane & 15;
  const int g = lane >> 4;
  const int nw = blockIdx.x * 64 + w * 16;
  const int mchunk = blockIdx.y * (nsteps * 32);

  const unsigned int* Zg = (const unsigned int*)Zghi;
  const unsigned int* Zt = (const unsigned int*)Zthi;

  // persistent A-frags: A[k] = Zn[n=nw+l15][c=8g..8g+8)
  short8 A[KK];
#pragma unroll
  for (int k = 0; k < KK; ++k)
    A[k] = as_s8(*(const u32x4*)&Zg[(size_t)(k * NN + nw + l15) * 16 + 4 * g]);

  f32x4 O[KK][2];
#pragma unroll
  for (int k = 0; k < KK; ++k)
#pragma unroll
    for (int ch = 0; ch < 2; ++ch) O[k][ch] = {0.0f, 0.0f, 0.0f, 0.0f};

  unsigned int* Pw = &Plds[w * (4 * 16 * PSTR)];

  for (int st = 0; st < nsteps; ++st) {
    const int mb = mchunk + st * 32;
    unsigned int mw[4];
#pragma unroll
    for (int r = 0; r < 4; ++r) mw[r] = mbits[(size_t)(nw + 4 * g + r) * 64 + (mb >> 5)];

#pragma unroll
    for (int sub = 0; sub < 2; ++sub) {
      // gram: S[n][m] for m = mb+16*sub+l15, all 8 k; B streamed from global (L1/L2)
      f32x4 S[KK];
#pragma unroll
      for (int k = 0; k < KK; ++k) {
        u32x4 bh = *(const u32x4*)&Zg[(size_t)(k * NN + mb + 16 * sub + l15) * 16 + 4 * g];
        f32x4 z = {0.0f, 0.0f, 0.0f, 0.0f};
        S[k] = MF(A[k], as_s8(bh), z);
      }
      // softmax across k (in-register; |S|<=~1 so no max-subtract)
#pragma unroll
      for (int r = 0; r < 4; ++r) {
        float e[KK];
        float sum = 0.0f;
#pragma unroll
        for (int k = 0; k < KK; ++k) { e[k] = __expf(S[k][r]); sum += e[k]; }
        const int ml = 16 * sub + l15;
        float fsc = ((mw[r] >> ml) & 1u) ? __builtin_amdgcn_rcpf(sum) : 0.0f;
#pragma unroll
        for (int k = 0; k < KK; ++k) S[k][r] = e[k] * fsc;
      }
      // pack P into per-kp regions (all writes before any read -> one lgkm wait)
#pragma unroll
      for (int kp = 0; kp < 4; ++kp)
#pragma unroll
        for (int r = 0; r < 4; ++r) {
          int n = 4 * g + r;
          Pw[kp * (16 * PSTR) + n * PSTR + 16 * sub + l15] =
              packp(S[2 * kp][r], S[2 * kp + 1][r]);
        }
    }

    // aggregate: O[k] += P_k . Zt_k ; P read back in A-layout, B streamed from global
#pragma unroll
    for (int kp = 0; kp < 4; ++kp) {
      const unsigned int* Pr = &Pw[kp * (16 * PSTR) + l15 * PSTR + 8 * g];
      u32x4 a0 = *(const u32x4*)Pr;
      u32x4 a1 = *(const u32x4*)(Pr + 4);
      UU pk0, pk1;
      pk0.u[0] = prm(a0.y, a0.x, SELLO); pk0.u[1] = prm(a0.w, a0.z, SELLO);
      pk0.u[2] = prm(a1.y, a1.x, SELLO); pk0.u[3] = prm(a1.w, a1.z, SELLO);
      pk1.u[0] = prm(a0.y, a0.x, SELHI); pk1.u[1] = prm(a0.w, a0.z, SELHI);
      pk1.u[2] = prm(a1.y, a1.x, SELHI); pk1.u[3] = prm(a1.w, a1.z, SELHI);
#pragma unroll
      for (int kk = 0; kk < 2; ++kk) {
        int k = 2 * kp + kk;
#pragma unroll
        for (int ch = 0; ch < 2; ++ch) {
          int c = 16 * ch + l15;
          u32x4 b = *(const u32x4*)&Zt[(size_t)k * (DD * NN / 2) + (size_t)c * (NN / 2) +
                                       (mb >> 1) + 4 * g];
          O[k][ch] = MF(kk ? pk1.v : pk0.v, as_s8(b), O[k][ch]);
        }
      }
    }
  }

  // write partials: part[chunk][k][n][c]
  float* dst = part + (size_t)blockIdx.y * ZSZ;
#pragma unroll
  for (int k = 0; k < KK; ++k)
#pragma unroll
    for (int ch = 0; ch < 2; ++ch) {
      f32x4 o = O[k][ch];
#pragma unroll
      for (int r = 0; r < 4; ++r)
        dst[(size_t)(k * NN + nw + 4 * g + r) * DD + 16 * ch + l15] = o[r];
    }
}

// ---------------- final: residual + reduce + l2norm + [N][K*D] output ----------------
__global__ __launch_bounds__(256) void ro_kernel(const float* __restrict__ Zin,
                                                 const float* __restrict__ part, int nc,
                                                 float* __restrict__ out) {
  const int n = blockIdx.x, t = threadIdx.x;
  const int k = t >> 5, c = t & 31;
  const size_t idx = (size_t)(k * NN + n) * DD + c;
  float v = Zin[idx];
  for (int j = 0; j < nc; ++j) v += part[(size_t)j * ZSZ + idx];
  float sq = v * v;
#pragma unroll
  for (int off = 16; off > 0; off >>= 1) sq += __shfl_xor(sq, off, 32);
  out[n * (KK * DD) + t] = v / fmaxf(sqrtf(sq), 1e-12f);
}

extern "C" void kernel_launch(void* const* d_in, const int* in_sizes, int n_in,
                              void* d_out, int out_size, void* d_ws, size_t ws_size,
                              hipStream_t stream) {
  const int* adj = (const int*)d_in[0];
  const float* feat = (const float*)d_in[1];
  const float* W = (const float*)d_in[2];
  const float* b = (const float*)d_in[3];
  float* out = (float*)d_out;

  int NC = 16;
  while (NC > 1) {
    size_t need = ((size_t)ZSZ * (2 + NC) + NN * 64) * 4 + (size_t)ZSZ * 2 * 2;
    if (need <= ws_size) break;
    NC >>= 1;
  }
  const int nsteps = NN / NC / 32;

  float* Z0 = (float*)d_ws;
  float* Z1 = Z0 + ZSZ;
  unsigned short* Zghi = (unsigned short*)(Z1 + ZSZ);
  unsigned short* Zthi = Zghi + ZSZ;
  unsigned int* mbits = (unsigned int*)(Zthi + ZSZ);
  float* part = (float*)(mbits + NN * 64);

  pm_kernel<<<NN + 256, 256, 0, stream>>>(feat, W, b, Z0, adj, mbits);

  // pack-only (Z0 already normalized)
  rp_kernel<<<512, 256, 0, stream>>>(Z0, part, 0, Z1, Zghi, Zthi);

  float* zi = Z0;
  float* zo = Z1;
  for (int it = 0; it < 4; ++it) {
    iter_kernel<<<dim3(32, NC), 256, 0, stream>>>(Zghi, Zthi, mbits, part, nsteps);
    if (it < 3) {
      rp_kernel<<<512, 256, 0, stream>>>(zi, part, NC, zo, Zghi, Zthi);
      float* tmp = zi; zi = zo; zo = tmp;
    } else {
      ro_kernel<<<NN, 256, 0, stream>>>(zi, part, NC, out);
    }
  }
}

// Round 6
// 202.191 us; speedup vs baseline: 1.3389x; 1.3389x over previous
//
#include <hip/hip_runtime.h>
#include <hip/hip_bf16.h>

#define NN 2048
#define KK 8
#define DD 32
#define ZSZ (KK * NN * DD)  // 524288

typedef __attribute__((ext_vector_type(8))) short short8;
typedef __attribute__((ext_vector_type(4))) float f32x4;
typedef __attribute__((ext_vector_type(4))) unsigned int u32x4;

union UU { u32x4 q; short8 v; unsigned int u[4]; };

#define SELHI 0x07060302u
#define SELLO 0x05040100u
#define PSTR 20  // per-kp P row stride (u32): 2-way writes (free), conflict-free b128 reads

__device__ __forceinline__ unsigned int prm(unsigned int a, unsigned int b, unsigned int sel) {
  return __builtin_amdgcn_perm(a, b, sel);
}
// round-to-nearest-even fp32 -> bf16 (scalar, rp only)
__device__ __forceinline__ unsigned int bfr(float x) {
  unsigned int u = __float_as_uint(x);
  return (u + 0x7fffu + ((u >> 16) & 1u)) >> 16;
}
// a->lo16, b->hi16 via v_cvt_pk_bf16_f32 (RNE)
__device__ __forceinline__ unsigned int packp(float a, float b) {
  union { __hip_bfloat162 h; unsigned int u; } cv;
  cv.h = __float22bfloat162_rn(make_float2(a, b));
  return cv.u;
}
__device__ __forceinline__ f32x4 MF(short8 a, short8 b, f32x4 c) {
  return __builtin_amdgcn_mfma_f32_16x16x32_bf16(a, b, c, 0, 0, 0);
}
__device__ __forceinline__ short8 as_s8(u32x4 x) { UU u; u.q = x; return u.v; }
__device__ __forceinline__ int swz(int m) { return (m ^ (m >> 2)) & 3; }

// ------- merged: proj (blocks 0..NN) + adj bitmask pack (blocks NN..NN+4096) -------
// mask part: 4096 blocks x 1024 ints, 4 independent rounds -> latency-parallel
__global__ __launch_bounds__(256) void pm_kernel(const float* __restrict__ feat,
                                                 const float* __restrict__ W,
                                                 const float* __restrict__ bias,
                                                 float* __restrict__ Z,
                                                 const int* __restrict__ adj,
                                                 unsigned int* __restrict__ mbits) {
  const int t = threadIdx.x;
  if (blockIdx.x < NN) {
    __shared__ float f[128];
    const int n = blockIdx.x;
    if (t < 128) f[t] = feat[n * 128 + t];
    __syncthreads();
    const int k = t >> 5, c = t & 31;
    float s = bias[k * DD + c];
    const float* w = W + (k * 128) * DD + c;
#pragma unroll 16
    for (int d = 0; d < 128; ++d) s = fmaf(f[d], w[d * DD], s);
    float sq = s * s;
#pragma unroll
    for (int off = 16; off > 0; off >>= 1) sq += __shfl_xor(sq, off, 32);
    Z[(k * NN + n) * DD + c] = s / fmaxf(sqrtf(sq), 1e-12f);
  } else {
    const int base = (blockIdx.x - NN) * 1024 + t;  // t = wave*64+lane within 256
    const int lane = t & 63;
    int v[4];
#pragma unroll
    for (int rr = 0; rr < 4; ++rr) v[rr] = adj[base + 256 * rr];
#pragma unroll
    for (int rr = 0; rr < 4; ++rr) {
      int idx = base + 256 * rr;
      unsigned long long b = __ballot(v[rr] > 0);
      if (lane == 0) mbits[idx >> 5] = (unsigned int)b;
      if (lane == 32) mbits[idx >> 5] = (unsigned int)(b >> 32);
    }
  }
}

// ------- fused: Z = l2norm(Zin + sum partials); write Z fp32 + hi plane + hi^T -------
__global__ __launch_bounds__(256) void rp_kernel(const float* __restrict__ Zin,
                                                 const float* __restrict__ part, int nc,
                                                 float* __restrict__ Zout,
                                                 unsigned short* __restrict__ Zghi,
                                                 unsigned short* __restrict__ Zthi) {
  __shared__ unsigned short T[DD][33];
  const int t = threadIdx.x;
  const int k = blockIdx.x >> 6, mt = blockIdx.x & 63;
  const int m0 = mt * 32;
  const int mloc = t >> 3, c4 = t & 7;
  const size_t idx = (size_t)(k * NN + m0 + mloc) * DD + 4 * c4;
  float4 v = *(const float4*)&Zin[idx];
  for (int j = 0; j < nc; ++j) {
    float4 p = *(const float4*)&part[(size_t)j * ZSZ + idx];
    v.x += p.x; v.y += p.y; v.z += p.z; v.w += p.w;
  }
  float sq = v.x * v.x + v.y * v.y + v.z * v.z + v.w * v.w;
  sq += __shfl_xor(sq, 1, 8);
  sq += __shfl_xor(sq, 2, 8);
  sq += __shfl_xor(sq, 4, 8);
  const float sc = 1.0f / fmaxf(sqrtf(sq), 1e-12f);
  float z[4] = {v.x * sc, v.y * sc, v.z * sc, v.w * sc};
  if (nc) *(float4*)&Zout[idx] = make_float4(z[0], z[1], z[2], z[3]);
  unsigned int hi[4];
#pragma unroll
  for (int e = 0; e < 4; ++e) {
    hi[e] = bfr(z[e]);
    T[4 * c4 + e][mloc] = (unsigned short)hi[e];
  }
  *(uint2*)&Zghi[idx] = make_uint2(hi[0] | (hi[1] << 16), hi[2] | (hi[3] << 16));
  __syncthreads();
  const int cloc = t >> 3, m4 = t & 7;
  unsigned int o0 = (unsigned int)T[cloc][4 * m4 + 0] | ((unsigned int)T[cloc][4 * m4 + 1] << 16);
  unsigned int o1 = (unsigned int)T[cloc][4 * m4 + 2] | ((unsigned int)T[cloc][4 * m4 + 3] << 16);
  *(uint2*)&Zthi[(size_t)k * DD * NN + (size_t)cloc * NN + m0 + 4 * m4] = make_uint2(o0, o1);
}

// ---------------- fused MFMA iteration: gram + softmax(k) + aggregate ----------------
// grid (32 n-blocks, NC chunks), block 256 (4 waves x 16 n-rows)
// LDS u32: [0,4096) hi tile [k][m][c], [4096,8192) hi^T tile [k][c][m],
//          [8192,..) per-wave per-kp P (4 kp regions of 16 rows x PSTR)
__global__ __launch_bounds__(256, 2) void iter_kernel(const unsigned short* __restrict__ Zghi,
                                                      const unsigned short* __restrict__ Zthi,
                                                      const unsigned int* __restrict__ mbits,
                                                      float* __restrict__ part, int nsteps) {
  __shared__ __align__(16) unsigned int lds[8192 + 4 * 4 * 16 * PSTR];  // 52 KB
  const int t = threadIdx.x;
  const int w = t >> 6;
  const int lane = t & 63;
  const int l15 = lane & 15;
  const int g = lane >> 4;
  const int nw = blockIdx.x * 64 + w * 16;
  const int mchunk = blockIdx.y * (nsteps * 32);

  const unsigned int* Zg = (const unsigned int*)Zghi;
  const unsigned int* Zt = (const unsigned int*)Zthi;

  // persistent A-frags (hi plane): A[k] = Zn[n=nw+l15][c=8g..8g+8)
  short8 A[KK];
#pragma unroll
  for (int k = 0; k < KK; ++k)
    A[k] = as_s8(*(const u32x4*)&Zg[(size_t)(k * NN + nw + l15) * 16 + 4 * g]);

  f32x4 O[KK][2];
#pragma unroll
  for (int k = 0; k < KK; ++k)
#pragma unroll
    for (int ch = 0; ch < 2; ++ch) O[k][ch] = {0.0f, 0.0f, 0.0f, 0.0f};

  // staging mapping: quad q fixed per thread, rows r = 64j + (t>>2)
  const int sqd = t & 3;
  const int sr0 = t >> 2;

  u32x4 Lgh[4], Lth[4];
  auto do_loads = [&](int mb) {
#pragma unroll
    for (int j = 0; j < 4; ++j) {
      int r = 64 * j + sr0;
      int k = r >> 5, rm = r & 31;
      Lgh[j] = *(const u32x4*)&Zg[(size_t)k * (NN * 16) + (size_t)(mb + rm) * 16 + sqd * 4];
      Lth[j] = *(const u32x4*)&Zt[(size_t)k * (NN * 16) + (size_t)rm * (NN / 2) + (mb >> 1) + sqd * 4];
    }
  };
  do_loads(mchunk);

  unsigned int* Pw = &lds[8192 + w * (4 * 16 * PSTR)];

  for (int st = 0; st < nsteps; ++st) {
    const int mb = mchunk + st * 32;
    __syncthreads();  // everyone done reading prev tiles
#pragma unroll
    for (int j = 0; j < 4; ++j) {
      int r = 64 * j + sr0;
      int rm = r & 31;
      int qs = (sqd ^ swz(rm)) << 2;
      *(u32x4*)&lds[r * 16 + qs] = Lgh[j];
      *(u32x4*)&lds[4096 + r * 16 + qs] = Lth[j];
    }
    __syncthreads();
    if (st + 1 < nsteps) do_loads(mb + 32);

    // ---- gram: S[n][m] = ahi . bhi (B from staged hi tile) ----
    f32x4 S[KK][2];
#pragma unroll
    for (int k = 0; k < KK; ++k) {
#pragma unroll
      for (int sub = 0; sub < 2; ++sub) {
        int m = 16 * sub + l15;
        u32x4 bh = *(const u32x4*)&lds[(k * 32 + m) * 16 + ((g ^ swz(m)) << 2)];
        f32x4 z = {0.0f, 0.0f, 0.0f, 0.0f};
        S[k][sub] = MF(A[k], as_s8(bh), z);
      }
    }

    // ---- softmax across k (in-register) ----
    unsigned int mw[4];
#pragma unroll
    for (int r = 0; r < 4; ++r) mw[r] = mbits[(size_t)(nw + 4 * g + r) * 64 + (mb >> 5)];
#pragma unroll
    for (int sub = 0; sub < 2; ++sub) {
#pragma unroll
      for (int r = 0; r < 4; ++r) {
        float e[KK];
        float sum = 0.0f;
#pragma unroll
        for (int k = 0; k < KK; ++k) { e[k] = __expf(S[k][sub][r]); sum += e[k]; }
        int ml = 16 * sub + l15;
        float f = ((mw[r] >> ml) & 1u) ? __builtin_amdgcn_rcpf(sum) : 0.0f;
#pragma unroll
        for (int k = 0; k < KK; ++k) S[k][sub][r] = e[k] * f;
      }
    }

    // ---- write ALL P (per-kp regions) before any read: one lgkm sync point ----
#pragma unroll
    for (int kp = 0; kp < 4; ++kp)
#pragma unroll
      for (int sub = 0; sub < 2; ++sub)
#pragma unroll
        for (int r = 0; r < 4; ++r) {
          int n = 4 * g + r;
          Pw[kp * (16 * PSTR) + n * PSTR + 16 * sub + l15] =
              packp(S[2 * kp][sub][r], S[2 * kp + 1][sub][r]);
        }

    // ---- per k-pair: P read-back (C->A transpose), aggregate from staged hi^T ----
#pragma unroll
    for (int kp = 0; kp < 4; ++kp) {
      const unsigned int* Pr = &Pw[kp * (16 * PSTR) + l15 * PSTR + 8 * g];
      u32x4 a0 = *(const u32x4*)Pr;
      u32x4 a1 = *(const u32x4*)(Pr + 4);
      UU pk0, pk1;
      pk0.u[0] = prm(a0.y, a0.x, SELLO); pk0.u[1] = prm(a0.w, a0.z, SELLO);
      pk0.u[2] = prm(a1.y, a1.x, SELLO); pk0.u[3] = prm(a1.w, a1.z, SELLO);
      pk1.u[0] = prm(a0.y, a0.x, SELHI); pk1.u[1] = prm(a0.w, a0.z, SELHI);
      pk1.u[2] = prm(a1.y, a1.x, SELHI); pk1.u[3] = prm(a1.w, a1.z, SELHI);
#pragma unroll
      for (int kk = 0; kk < 2; ++kk) {
        int k = 2 * kp + kk;
#pragma unroll
        for (int ch = 0; ch < 2; ++ch) {
          int c = 16 * ch + l15;
          u32x4 b = *(const u32x4*)&lds[4096 + (k * 32 + c) * 16 + ((g ^ swz(c)) << 2)];
          O[k][ch] = MF(kk ? pk1.v : pk0.v, as_s8(b), O[k][ch]);
        }
      }
    }
  }

  // ---- write partials: part[chunk][k][n][c] ----
  float* dst = part + (size_t)blockIdx.y * ZSZ;
#pragma unroll
  for (int k = 0; k < KK; ++k)
#pragma unroll
    for (int ch = 0; ch < 2; ++ch) {
      f32x4 o = O[k][ch];
#pragma unroll
      for (int r = 0; r < 4; ++r)
        dst[(size_t)(k * NN + nw + 4 * g + r) * DD + 16 * ch + l15] = o[r];
    }
}

// ---------------- final: residual + reduce + l2norm + [N][K*D] output ----------------
__global__ __launch_bounds__(256) void ro_kernel(const float* __restrict__ Zin,
                                                 const float* __restrict__ part, int nc,
                                                 float* __restrict__ out) {
  const int n = blockIdx.x, t = threadIdx.x;
  const int k = t >> 5, c = t & 31;
  const size_t idx = (size_t)(k * NN + n) * DD + c;
  float v = Zin[idx];
  for (int j = 0; j < nc; ++j) v += part[(size_t)j * ZSZ + idx];
  float sq = v * v;
#pragma unroll
  for (int off = 16; off > 0; off >>= 1) sq += __shfl_xor(sq, off, 32);
  out[n * (KK * DD) + t] = v / fmaxf(sqrtf(sq), 1e-12f);
}

extern "C" void kernel_launch(void* const* d_in, const int* in_sizes, int n_in,
                              void* d_out, int out_size, void* d_ws, size_t ws_size,
                              hipStream_t stream) {
  const int* adj = (const int*)d_in[0];
  const float* feat = (const float*)d_in[1];
  const float* W = (const float*)d_in[2];
  const float* b = (const float*)d_in[3];
  float* out = (float*)d_out;

  int NC = 16;
  while (NC > 1) {
    size_t need = ((size_t)ZSZ * (2 + NC) + NN * 64) * 4 + (size_t)ZSZ * 2 * 2;
    if (need <= ws_size) break;
    NC >>= 1;
  }
  const int nsteps = NN / NC / 32;

  float* Z0 = (float*)d_ws;
  float* Z1 = Z0 + ZSZ;
  unsigned short* Zghi = (unsigned short*)(Z1 + ZSZ);
  unsigned short* Zthi = Zghi + ZSZ;
  unsigned int* mbits = (unsigned int*)(Zthi + ZSZ);
  float* part = (float*)(mbits + NN * 64);

  pm_kernel<<<NN + 4096, 256, 0, stream>>>(feat, W, b, Z0, adj, mbits);

  // pack-only (Z0 already normalized)
  rp_kernel<<<512, 256, 0, stream>>>(Z0, part, 0, Z1, Zghi, Zthi);

  float* zi = Z0;
  float* zo = Z1;
  for (int it = 0; it < 4; ++it) {
    iter_kernel<<<dim3(32, NC), 256, 0, stream>>>(Zghi, Zthi, mbits, part, nsteps);
    if (it < 3) {
      rp_kernel<<<512, 256, 0, stream>>>(zi, part, NC, zo, Zghi, Zthi);
      float* tmp = zi; zi = zo; zo = tmp;
    } else {
      ro_kernel<<<NN, 256, 0, stream>>>(zi, part, NC, out);
    }
  }
}